// Round 1
// baseline (408.261 us; speedup 1.0000x reference)
//
#include <hip/hip_runtime.h>

// InstanceWiseAveragePooling on MI355X.
// out[p,ch] = mean over ALL feats elements (3 channels, whole batch) whose
// pixel's inst == inst[p]. Classes are disjoint and cover every pixel
// (inst in {0,1,2}), so the output never contains original feats values.
//
// Pipeline (all HBM-streaming, no atomics):
//   1) reduce_k:   1024 blocks x 256 thr, grid-stride over pixels/4.
//                  Per-thread double sums + uint counts per class,
//                  wave-shuffle + LDS reduce, write partials to d_ws.
//   2) finalize_k: 1 block reduces 1024 partials -> float mean[3] in d_ws.
//   3) scatter_k:  out[3p..3p+2] = mean[inst[p]], float4 stores.

#define RBLK 1024

__device__ inline double wred_d(double v) {
#pragma unroll
    for (int off = 32; off; off >>= 1) v += __shfl_down(v, off, 64);
    return v;
}
__device__ inline unsigned wred_u(unsigned v) {
#pragma unroll
    for (int off = 32; off; off >>= 1) v += __shfl_down(v, off, 64);
    return v;
}

__global__ __launch_bounds__(256) void reduce_k(const float* __restrict__ feats,
                                                const int* __restrict__ inst,
                                                double* __restrict__ psum,
                                                unsigned* __restrict__ pcnt,
                                                int npix4) {
    int tid = blockIdx.x * 256 + threadIdx.x;
    int stride = gridDim.x * 256;
    double s0 = 0.0, s1 = 0.0, s2 = 0.0;
    unsigned c0 = 0, c1 = 0, c2 = 0;
    const int4* inst4 = (const int4*)inst;
    for (int i = tid; i < npix4; i += stride) {
        int4 cls = inst4[i];
        const float4* f = (const float4*)(feats + (size_t)i * 12);
        float4 a = f[0], b = f[1], c = f[2];
        // pixel 0: a.x a.y a.z | pixel 1: a.w b.x b.y
        // pixel 2: b.z b.w c.x | pixel 3: c.y c.z c.w
        double d0 = (double)(a.x + a.y + a.z);
        double d1 = (double)(a.w + b.x + b.y);
        double d2 = (double)(b.z + b.w + c.x);
        double d3 = (double)(c.y + c.z + c.w);
        s0 += (cls.x == 0) ? d0 : 0.0;
        s1 += (cls.x == 1) ? d0 : 0.0;
        s2 += (cls.x == 2) ? d0 : 0.0;
        s0 += (cls.y == 0) ? d1 : 0.0;
        s1 += (cls.y == 1) ? d1 : 0.0;
        s2 += (cls.y == 2) ? d1 : 0.0;
        s0 += (cls.z == 0) ? d2 : 0.0;
        s1 += (cls.z == 1) ? d2 : 0.0;
        s2 += (cls.z == 2) ? d2 : 0.0;
        s0 += (cls.w == 0) ? d3 : 0.0;
        s1 += (cls.w == 1) ? d3 : 0.0;
        s2 += (cls.w == 2) ? d3 : 0.0;
        c0 += (unsigned)(cls.x == 0) + (unsigned)(cls.y == 0) +
              (unsigned)(cls.z == 0) + (unsigned)(cls.w == 0);
        c1 += (unsigned)(cls.x == 1) + (unsigned)(cls.y == 1) +
              (unsigned)(cls.z == 1) + (unsigned)(cls.w == 1);
        c2 += (unsigned)(cls.x == 2) + (unsigned)(cls.y == 2) +
              (unsigned)(cls.z == 2) + (unsigned)(cls.w == 2);
    }
    s0 = wred_d(s0); s1 = wred_d(s1); s2 = wred_d(s2);
    c0 = wred_u(c0); c1 = wred_u(c1); c2 = wred_u(c2);

    __shared__ double ls[4][3];
    __shared__ unsigned lc[4][3];
    int wid = threadIdx.x >> 6;
    int lane = threadIdx.x & 63;
    if (lane == 0) {
        ls[wid][0] = s0; ls[wid][1] = s1; ls[wid][2] = s2;
        lc[wid][0] = c0; lc[wid][1] = c1; lc[wid][2] = c2;
    }
    __syncthreads();
    if (threadIdx.x < 3) {
        int c = threadIdx.x;
        double s = ls[0][c] + ls[1][c] + ls[2][c] + ls[3][c];
        unsigned cc = lc[0][c] + lc[1][c] + lc[2][c] + lc[3][c];
        psum[blockIdx.x * 3 + c] = s;
        pcnt[blockIdx.x * 3 + c] = cc;
    }
}

__global__ __launch_bounds__(256) void finalize_k(const double* __restrict__ psum,
                                                  const unsigned* __restrict__ pcnt,
                                                  float* __restrict__ mean,
                                                  int nblk) {
    double s0 = 0.0, s1 = 0.0, s2 = 0.0;
    unsigned c0 = 0, c1 = 0, c2 = 0;
    for (int i = threadIdx.x; i < nblk; i += 256) {
        s0 += psum[i * 3 + 0]; s1 += psum[i * 3 + 1]; s2 += psum[i * 3 + 2];
        c0 += pcnt[i * 3 + 0]; c1 += pcnt[i * 3 + 1]; c2 += pcnt[i * 3 + 2];
    }
    s0 = wred_d(s0); s1 = wred_d(s1); s2 = wred_d(s2);
    c0 = wred_u(c0); c1 = wred_u(c1); c2 = wred_u(c2);

    __shared__ double ls[4][3];
    __shared__ unsigned lc[4][3];
    int wid = threadIdx.x >> 6;
    int lane = threadIdx.x & 63;
    if (lane == 0) {
        ls[wid][0] = s0; ls[wid][1] = s1; ls[wid][2] = s2;
        lc[wid][0] = c0; lc[wid][1] = c1; lc[wid][2] = c2;
    }
    __syncthreads();
    if (threadIdx.x < 3) {
        int c = threadIdx.x;
        double s = ls[0][c] + ls[1][c] + ls[2][c] + ls[3][c];
        unsigned cc = lc[0][c] + lc[1][c] + lc[2][c] + lc[3][c];
        // count includes the 3-channel broadcast in the reference
        mean[c] = (float)(s / (3.0 * (double)cc));
    }
}

__global__ __launch_bounds__(256) void scatter_k(const int* __restrict__ inst,
                                                 const float* __restrict__ mean,
                                                 float* __restrict__ out,
                                                 int npix4) {
    int i = blockIdx.x * 256 + threadIdx.x;
    if (i >= npix4) return;
    float m0 = mean[0], m1 = mean[1], m2 = mean[2];
    int4 cls = ((const int4*)inst)[i];
    float vx = (cls.x == 1) ? m1 : ((cls.x == 2) ? m2 : m0);
    float vy = (cls.y == 1) ? m1 : ((cls.y == 2) ? m2 : m0);
    float vz = (cls.z == 1) ? m1 : ((cls.z == 2) ? m2 : m0);
    float vw = (cls.w == 1) ? m1 : ((cls.w == 2) ? m2 : m0);
    float4* o = (float4*)(out + (size_t)i * 12);
    o[0] = make_float4(vx, vx, vx, vy);
    o[1] = make_float4(vy, vy, vz, vz);
    o[2] = make_float4(vz, vw, vw, vw);
}

extern "C" void kernel_launch(void* const* d_in, const int* in_sizes, int n_in,
                              void* d_out, int out_size, void* d_ws, size_t ws_size,
                              hipStream_t stream) {
    const float* feats = (const float*)d_in[0];
    const int* inst = (const int*)d_in[1];
    float* out = (float*)d_out;

    int npix = in_sizes[1];        // 16*1024*1024, divisible by 4
    int npix4 = npix >> 2;

    double* psum = (double*)d_ws;                 // RBLK*3 doubles
    unsigned* pcnt = (unsigned*)(psum + RBLK * 3); // RBLK*3 uints
    float* mean = (float*)(pcnt + RBLK * 3);       // 3 floats

    reduce_k<<<RBLK, 256, 0, stream>>>(feats, inst, psum, pcnt, npix4);
    finalize_k<<<1, 256, 0, stream>>>(psum, pcnt, mean, RBLK);
    scatter_k<<<(npix4 + 255) / 256, 256, 0, stream>>>(inst, mean, out, npix4);
}